// Round 5
// baseline (783.058 us; speedup 1.0000x reference)
//
#include <hip/hip_runtime.h>
#include <math.h>

#define DIM 64
#define NW 4            // waves per block
#define NPB 4           // nodes per wave per iteration
#define CAP 64          // per-row edge bucket capacity (mean degree = 25)
#define PIPE 4          // software-pipeline depth == gelu batch width

__device__ __forceinline__ float waveReduceSum(float v) {
    #pragma unroll
    for (int off = 1; off < 64; off <<= 1)
        v += __shfl_xor(v, off, 64);
    return v;
}

// ---------------- Kernel A: LayerNorm + QKV projection ----------------
// k and v are written PACKED as float2 so agg's gather is one 8B load.
__global__ __launch_bounds__(256) void qkv_kernel(
    const float* __restrict__ node_feat,
    const float* __restrict__ ln_g, const float* __restrict__ ln_b,
    const float* __restrict__ qkv_w, const float* __restrict__ qkv_b,
    float* __restrict__ q, float2* __restrict__ kv,
    int N)
{
    __shared__ float  wlds[64 * 192];        // [d][j_permuted]  48 KB
    __shared__ float4 xs[NW][NPB][16];       // per-wave x rows   4 KB
    const int wave = threadIdx.x >> 6, lane = threadIdx.x & 63;

    for (int idx = threadIdx.x; idx < 64 * 192; idx += 256) {
        int d = idx / 192, j = idx - d * 192;
        int jj = j & 63, sec = j >> 6;                 // sec: 0=q 1=k 2=v
        int c = 12 * (jj >> 2) + (jj & 3) + 4 * sec;   // h*12 + t + 4*sec
        wlds[idx] = qkv_w[d * 192 + c];
    }
    const int c0 = 12 * (lane >> 2) + (lane & 3);
    const float b0 = qkv_b[c0], b1 = qkv_b[c0 + 4], b2 = qkv_b[c0 + 8];
    const float gg = ln_g[lane], bb = ln_b[lane];
    __syncthreads();

    const int nstride = gridDim.x * NW * NPB;
    for (int n0 = (blockIdx.x * NW + wave) * NPB; n0 < N; n0 += nstride) {
        const int cnt = min(NPB, N - n0);
        float acc0[NPB], acc1[NPB], acc2[NPB];
        #pragma unroll
        for (int i = 0; i < NPB; ++i) {
            acc0[i] = b0; acc1[i] = b1; acc2[i] = b2;
            if (i < cnt) {
                float nf = node_feat[(size_t)(n0 + i) * DIM + lane];
                float mu = waveReduceSum(nf) * (1.0f / 64.0f);
                float dv = nf - mu;
                float var = waveReduceSum(dv * dv) * (1.0f / 64.0f);
                float x = dv * rsqrtf(var + 1e-5f) * gg + bb;
                ((float*)&xs[wave][i][0])[lane] = x;
            }
        }
        #pragma unroll 4
        for (int d4 = 0; d4 < 16; ++d4) {
            float4 xv[NPB];
            #pragma unroll
            for (int i = 0; i < NPB; ++i) xv[i] = xs[wave][i][d4];
            #pragma unroll
            for (int u = 0; u < 4; ++u) {
                int d = d4 * 4 + u;
                float w0 = wlds[d * 192 + lane];
                float w1 = wlds[d * 192 + lane + 64];
                float w2 = wlds[d * 192 + lane + 128];
                #pragma unroll
                for (int i = 0; i < NPB; ++i) {
                    float xd = (&xv[i].x)[u];
                    acc0[i] = fmaf(xd, w0, acc0[i]);
                    acc1[i] = fmaf(xd, w1, acc1[i]);
                    acc2[i] = fmaf(xd, w2, acc2[i]);
                }
            }
        }
        #pragma unroll
        for (int i = 0; i < NPB; ++i) if (i < cnt) {
            size_t off = (size_t)(n0 + i) * DIM + lane;
            q[off] = acc0[i];
            kv[off] = make_float2(acc1[i], acc2[i]);
        }
    }
}

// ---------------- Kernel B: input_dot + fused edge-bucket scatter ------------
__global__ __launch_bounds__(256) void vec_kernel(
    const float* __restrict__ node_vec,
    const float* __restrict__ vec_w,
    float* __restrict__ input_dot,
    const int* __restrict__ row,
    const int* __restrict__ col,
    int* __restrict__ deg,
    int2* __restrict__ perm2,
    int* __restrict__ ovcnt,
    int* __restrict__ ovlist,
    int N, int E)
{
    __shared__ float  vlds[64 * 128];          // 32 KB
    __shared__ float4 nvs[NW][NPB][3][16];     // 12 KB
    const int wave = threadIdx.x >> 6, lane = threadIdx.x & 63;

    for (int idx = threadIdx.x; idx < 64 * 128; idx += 256)
        vlds[idx] = vec_w[idx];
    __syncthreads();

    const int nstride = gridDim.x * NW * NPB;
    for (int n0 = (blockIdx.x * NW + wave) * NPB; n0 < N; n0 += nstride) {
        const int cnt = min(NPB, N - n0);
        float a0[NPB][3], a1[NPB][3];
        #pragma unroll
        for (int i = 0; i < NPB; ++i) {
            #pragma unroll
            for (int s = 0; s < 3; ++s) {
                a0[i][s] = 0.f; a1[i][s] = 0.f;
                if (i < cnt)
                    ((float*)&nvs[wave][i][s][0])[lane] =
                        node_vec[((size_t)(n0 + i) * 3 + s) * DIM + lane];
            }
        }
        #pragma unroll 2
        for (int d4 = 0; d4 < 16; ++d4) {
            #pragma unroll
            for (int u = 0; u < 4; ++u) {
                int d = d4 * 4 + u;
                float w0 = vlds[d * 128 + lane];
                float w1 = vlds[d * 128 + lane + 64];
                #pragma unroll
                for (int i = 0; i < NPB; ++i) {
                    #pragma unroll
                    for (int s = 0; s < 3; ++s) {
                        float nv = ((float*)&nvs[wave][i][s][d4])[u];
                        a0[i][s] = fmaf(nv, w0, a0[i][s]);
                        a1[i][s] = fmaf(nv, w1, a1[i][s]);
                    }
                }
            }
        }
        #pragma unroll
        for (int i = 0; i < NPB; ++i) if (i < cnt) {
            size_t off = (size_t)(n0 + i) * DIM + lane;
            input_dot[off] = a0[i][0] * a1[i][0] + a0[i][1] * a1[i][1]
                           + a0[i][2] * a1[i][2];
        }
    }

    // ---- edge scatter phase: bucket edges by destination row ----
    for (int e = blockIdx.x * 256 + threadIdx.x; e < E; e += gridDim.x * 256) {
        int r = row[e];
        int slot = atomicAdd(&deg[r], 1);
        if (slot < CAP) {
            perm2[(size_t)r * CAP + slot] = make_int2(e, col[e]);
        } else {
            int o = atomicAdd(ovcnt, 1);   // ovlist sized E: can't overflow
            ovlist[o] = e;
        }
    }
}

// ---------------- Kernel O: overflow edges (deg > CAP; normally empty) -------
__global__ __launch_bounds__(256) void ovf_kernel(
    const float* __restrict__ q,
    const float2* __restrict__ kv,
    const float* __restrict__ edge_feat,
    const float* __restrict__ radial,
    const int* __restrict__ row,
    const int* __restrict__ col,
    const int* __restrict__ ovcnt,
    const int* __restrict__ ovlist,
    float* __restrict__ m_agg)
{
    const int wave = threadIdx.x >> 6, lane = threadIdx.x & 63;
    const int ovn = *ovcnt;
    for (int i = blockIdx.x * NW + wave; i < ovn; i += gridDim.x * NW) {
        int e = ovlist[i];
        int r = row[e], c = col[e];
        float2 kvv = kv[(size_t)c * DIM + lane];
        float p = q[(size_t)r * DIM + lane] * kvv.x;
        p += __shfl_xor(p, 1, 64);
        p += __shfl_xor(p, 2, 64);
        float g = 0.5f * p * (1.0f + erff(p * 0.70710678118654752f));
        float a = g * radial[e];
        float m = kvv.y * edge_feat[(size_t)e * DIM + lane] * a;
        atomicAdd(&m_agg[(size_t)r * DIM + lane], m);
    }
}

// ---------------- Kernel C: aggregation + fused output projection ------------
// 4-deep pipeline AND 4-edge-batched GELU: 64 lanes hold only 16 unique head
// dots, so per-lane erff was 4x redundant (round-4: VALUBusy 88%). One erf now
// serves 4 edges: lane l = edge (l&3), head (l>>2); broadcast back via shfl.
__global__ __launch_bounds__(256) void agg_kernel(
    const float* __restrict__ q,
    const float2* __restrict__ kv,
    const float* __restrict__ edge_feat, // (E,64)
    const float* __restrict__ radial,
    const int2* __restrict__ perm2,
    const int* __restrict__ deg,
    const float* __restrict__ m_agg,     // overflow contributions only
    const float* __restrict__ input_dot,
    const float* __restrict__ out_w,     // (64,128) — L1-resident, not staged
    const float* __restrict__ out_b,     // (128,)
    float* __restrict__ result,          // (N,64)
    int N)
{
    __shared__ float accs[NW][64];       // 1 KB: per-wave row transpose
    const int wave = threadIdx.x >> 6, lane = threadIdx.x & 63;
    const int l3 = lane & 3, lh = lane & 60;
    const float ob0 = out_b[lane], ob1 = out_b[lane + 64];

#define ISSUE(J, S) do {                                                   \
        if ((J) < cn) {                                                    \
            int e_ = __shfl(myec.x, (J), 64);                              \
            int c_ = __shfl(myec.y, (J), 64);                              \
            kvq[S] = kv[(c_ << 6) + lane];                                 \
            eq[S] = __builtin_nontemporal_load(                            \
                        &edge_feat[((size_t)(unsigned)e_ << 6) + lane]);   \
        }                                                                  \
    } while (0)

    for (int n = blockIdx.x * NW + wave; n < N; n += gridDim.x * NW) {
        const int draw = deg[n];
        const int cn = min(draw, CAP);
        int2 myec = make_int2(0, 0);
        float myrad = 0.0f;
        if (lane < cn) {
            myec = perm2[(size_t)n * CAP + lane];   // coalesced 8B
            myrad = radial[myec.x];                 // 5 MB, cache-resident
        }
        const float qd = q[(n << 6) + lane];
        float idv = input_dot[(n << 6) + lane];     // early issue, used late

        float2 kvq[PIPE]; float eq[PIPE];
        #pragma unroll
        for (int s = 0; s < PIPE; ++s) ISSUE(s, s);

        float acc = 0.0f;
        for (int j0 = 0; j0 < cn; j0 += PIPE) {
            float p[PIPE], ve[PIPE], rad[PIPE];
            #pragma unroll
            for (int s = 0; s < PIPE; ++s) {
                const int j = j0 + s;
                if (j < cn) {
                    float kd = kvq[s].x, vd = kvq[s].y, ef = eq[s];
                    ISSUE(j + PIPE, s);             // refill stage early
                    ve[s] = vd * ef;
                    rad[s] = __shfl(myrad, j, 64);
                    float pp = qd * kd;
                    pp += __shfl_xor(pp, 1, 64);
                    pp += __shfl_xor(pp, 2, 64);    // head dot in all 4 lanes
                    p[s] = pp;
                } else { p[s] = 0.f; ve[s] = 0.f; rad[s] = 0.f; }
            }
            // one gelu serves 4 edges: lane l = edge (l&3), head (l>>2)
            float psel = l3 == 0 ? p[0] : l3 == 1 ? p[1]
                       : l3 == 2 ? p[2] : p[3];
            float rsel = l3 == 0 ? rad[0] : l3 == 1 ? rad[1]
                       : l3 == 2 ? rad[2] : rad[3];
            float aval = 0.5f * psel *
                         (1.0f + erff(psel * 0.70710678118654752f)) * rsel;
            #pragma unroll
            for (int s = 0; s < PIPE; ++s) {
                if (j0 + s < cn)
                    acc = fmaf(ve[s], __shfl(aval, lh + s, 64), acc);
            }
        }

        // wave-uniform, ~never-taken: fold in overflow atomics
        if (draw > CAP) acc += m_agg[(n << 6) + lane];

        // ---- fused output projection: out = acc_row @ out_w + out_b ----
        accs[wave][lane] = acc;                     // same-wave LDS transpose
        float o0 = ob0, o1 = ob1;
        #pragma unroll 8
        for (int d = 0; d < 64; ++d) {
            float md = accs[wave][d];               // LDS broadcast
            o0 = fmaf(md, out_w[d * 128 + lane], o0);
            o1 = fmaf(md, out_w[d * 128 + 64 + lane], o1);
        }
        result[(n << 6) + lane] = idv * o0 + o1;
    }
#undef ISSUE
}

extern "C" void kernel_launch(void* const* d_in, const int* in_sizes, int n_in,
                              void* d_out, int out_size, void* d_ws, size_t ws_size,
                              hipStream_t stream)
{
    const float* node_feat = (const float*)d_in[0];
    const float* edge_feat = (const float*)d_in[1];
    const float* node_vec  = (const float*)d_in[2];
    const float* radial    = (const float*)d_in[3];
    const float* ln_g      = (const float*)d_in[4];
    const float* ln_b      = (const float*)d_in[5];
    const float* qkv_w     = (const float*)d_in[6];
    const float* qkv_b     = (const float*)d_in[7];
    const float* vec_w     = (const float*)d_in[8];
    const float* out_w     = (const float*)d_in[9];
    const float* out_b     = (const float*)d_in[10];
    const int*   row       = (const int*)d_in[11];
    const int*   col       = (const int*)d_in[12];

    const int N = in_sizes[0] / DIM;   // 50000
    const int E = in_sizes[3];         // 1250000

    float*  ws    = (float*)d_ws;
    float*  q     = ws;                                   // N*64
    float2* kv    = (float2*)(q + (size_t)N * DIM);       // N*64 float2
    float*  idot  = (float*)(kv + (size_t)N * DIM);       // N*64
    float*  m_agg = idot + (size_t)N * DIM;               // N*64
    int2*   perm2 = (int2*)(m_agg + (size_t)N * DIM);     // N*CAP int2
    int*    deg   = (int*)(perm2 + (size_t)N * CAP);      // N ints
    int*    ovcnt = deg + N;                              // 1 int
    int*    ovlist= ovcnt + 1;                            // E ints

    const int grid_nodes = 768;
    const int grid_agg   = (N + NW - 1) / NW;             // 1 row per wave

    // zero counters + m_agg (overflow-atomic target); graph-capturable
    hipMemsetAsync(m_agg, 0, (size_t)N * DIM * sizeof(float), stream);
    hipMemsetAsync(deg,   0, (size_t)(N + 1) * sizeof(int), stream);

    qkv_kernel<<<grid_nodes, 256, 0, stream>>>(node_feat, ln_g, ln_b,
                                               qkv_w, qkv_b, q, kv, N);
    vec_kernel<<<grid_nodes, 256, 0, stream>>>(node_vec, vec_w, idot,
                                               row, col, deg, perm2,
                                               ovcnt, ovlist, N, E);
    ovf_kernel<<<256, 256, 0, stream>>>(q, kv, edge_feat, radial,
                                        row, col, ovcnt, ovlist, m_agg);
    agg_kernel<<<grid_agg, 256, 0, stream>>>(q, kv, edge_feat, radial,
                                             perm2, deg, m_agg, idot,
                                             out_w, out_b, (float*)d_out, N);
}

// Round 7
// 759.630 us; speedup vs baseline: 1.0308x; 1.0308x over previous
//
#include <hip/hip_runtime.h>
#include <math.h>

#define DIM 64
#define NW 4            // waves per block
#define NPB 4           // nodes per wave per iteration
#define CAP 64          // per-row edge bucket capacity (mean degree = 25)
#define PIPE 4          // software-pipeline depth == gelu batch width

__device__ __forceinline__ float waveReduceSum(float v) {
    #pragma unroll
    for (int off = 1; off < 64; off <<= 1)
        v += __shfl_xor(v, off, 64);
    return v;
}

// ---------------- Kernel A: LayerNorm + QKV projection ----------------
// k and v are written PACKED as float2 so agg's gather is one 8B load.
__global__ __launch_bounds__(256) void qkv_kernel(
    const float* __restrict__ node_feat,
    const float* __restrict__ ln_g, const float* __restrict__ ln_b,
    const float* __restrict__ qkv_w, const float* __restrict__ qkv_b,
    float* __restrict__ q, float2* __restrict__ kv,
    int N)
{
    __shared__ float  wlds[64 * 192];        // [d][j_permuted]  48 KB
    __shared__ float4 xs[NW][NPB][16];       // per-wave x rows   4 KB
    const int wave = threadIdx.x >> 6, lane = threadIdx.x & 63;

    for (int idx = threadIdx.x; idx < 64 * 192; idx += 256) {
        int d = idx / 192, j = idx - d * 192;
        int jj = j & 63, sec = j >> 6;                 // sec: 0=q 1=k 2=v
        int c = 12 * (jj >> 2) + (jj & 3) + 4 * sec;   // h*12 + t + 4*sec
        wlds[idx] = qkv_w[d * 192 + c];
    }
    const int c0 = 12 * (lane >> 2) + (lane & 3);
    const float b0 = qkv_b[c0], b1 = qkv_b[c0 + 4], b2 = qkv_b[c0 + 8];
    const float gg = ln_g[lane], bb = ln_b[lane];
    __syncthreads();

    const int nstride = gridDim.x * NW * NPB;
    for (int n0 = (blockIdx.x * NW + wave) * NPB; n0 < N; n0 += nstride) {
        const int cnt = min(NPB, N - n0);
        float acc0[NPB], acc1[NPB], acc2[NPB];
        #pragma unroll
        for (int i = 0; i < NPB; ++i) {
            acc0[i] = b0; acc1[i] = b1; acc2[i] = b2;
            if (i < cnt) {
                float nf = node_feat[(size_t)(n0 + i) * DIM + lane];
                float mu = waveReduceSum(nf) * (1.0f / 64.0f);
                float dv = nf - mu;
                float var = waveReduceSum(dv * dv) * (1.0f / 64.0f);
                float x = dv * rsqrtf(var + 1e-5f) * gg + bb;
                ((float*)&xs[wave][i][0])[lane] = x;
            }
        }
        #pragma unroll 4
        for (int d4 = 0; d4 < 16; ++d4) {
            float4 xv[NPB];
            #pragma unroll
            for (int i = 0; i < NPB; ++i) xv[i] = xs[wave][i][d4];
            #pragma unroll
            for (int u = 0; u < 4; ++u) {
                int d = d4 * 4 + u;
                float w0 = wlds[d * 192 + lane];
                float w1 = wlds[d * 192 + lane + 64];
                float w2 = wlds[d * 192 + lane + 128];
                #pragma unroll
                for (int i = 0; i < NPB; ++i) {
                    float xd = (&xv[i].x)[u];
                    acc0[i] = fmaf(xd, w0, acc0[i]);
                    acc1[i] = fmaf(xd, w1, acc1[i]);
                    acc2[i] = fmaf(xd, w2, acc2[i]);
                }
            }
        }
        #pragma unroll
        for (int i = 0; i < NPB; ++i) if (i < cnt) {
            size_t off = (size_t)(n0 + i) * DIM + lane;
            q[off] = acc0[i];
            kv[off] = make_float2(acc1[i], acc2[i]);
        }
    }
}

// ---------------- Kernel B: input_dot + fused edge-bucket scatter ------------
__global__ __launch_bounds__(256) void vec_kernel(
    const float* __restrict__ node_vec,
    const float* __restrict__ vec_w,
    float* __restrict__ input_dot,
    const int* __restrict__ row,
    const int* __restrict__ col,
    int* __restrict__ deg,
    int2* __restrict__ perm2,
    int* __restrict__ ovcnt,
    int* __restrict__ ovlist,
    int N, int E)
{
    __shared__ float  vlds[64 * 128];          // 32 KB
    __shared__ float4 nvs[NW][NPB][3][16];     // 12 KB
    const int wave = threadIdx.x >> 6, lane = threadIdx.x & 63;

    for (int idx = threadIdx.x; idx < 64 * 128; idx += 256)
        vlds[idx] = vec_w[idx];
    __syncthreads();

    const int nstride = gridDim.x * NW * NPB;
    for (int n0 = (blockIdx.x * NW + wave) * NPB; n0 < N; n0 += nstride) {
        const int cnt = min(NPB, N - n0);
        float a0[NPB][3], a1[NPB][3];
        #pragma unroll
        for (int i = 0; i < NPB; ++i) {
            #pragma unroll
            for (int s = 0; s < 3; ++s) {
                a0[i][s] = 0.f; a1[i][s] = 0.f;
                if (i < cnt)
                    ((float*)&nvs[wave][i][s][0])[lane] =
                        node_vec[((size_t)(n0 + i) * 3 + s) * DIM + lane];
            }
        }
        #pragma unroll 2
        for (int d4 = 0; d4 < 16; ++d4) {
            #pragma unroll
            for (int u = 0; u < 4; ++u) {
                int d = d4 * 4 + u;
                float w0 = vlds[d * 128 + lane];
                float w1 = vlds[d * 128 + lane + 64];
                #pragma unroll
                for (int i = 0; i < NPB; ++i) {
                    #pragma unroll
                    for (int s = 0; s < 3; ++s) {
                        float nv = ((float*)&nvs[wave][i][s][d4])[u];
                        a0[i][s] = fmaf(nv, w0, a0[i][s]);
                        a1[i][s] = fmaf(nv, w1, a1[i][s]);
                    }
                }
            }
        }
        #pragma unroll
        for (int i = 0; i < NPB; ++i) if (i < cnt) {
            size_t off = (size_t)(n0 + i) * DIM + lane;
            input_dot[off] = a0[i][0] * a1[i][0] + a0[i][1] * a1[i][1]
                           + a0[i][2] * a1[i][2];
        }
    }

    // ---- edge scatter phase: bucket edges by destination row ----
    for (int e = blockIdx.x * 256 + threadIdx.x; e < E; e += gridDim.x * 256) {
        int r = row[e];
        int slot = atomicAdd(&deg[r], 1);
        if (slot < CAP) {
            perm2[(size_t)r * CAP + slot] = make_int2(e, col[e]);
        } else {
            int o = atomicAdd(ovcnt, 1);   // ovlist sized E: can't overflow
            ovlist[o] = e;
        }
    }
}

// ---------------- Kernel O: overflow edges (deg > CAP; normally empty) -------
__global__ __launch_bounds__(256) void ovf_kernel(
    const float* __restrict__ q,
    const float2* __restrict__ kv,
    const float* __restrict__ edge_feat,
    const float* __restrict__ radial,
    const int* __restrict__ row,
    const int* __restrict__ col,
    const int* __restrict__ ovcnt,
    const int* __restrict__ ovlist,
    float* __restrict__ m_agg)
{
    const int wave = threadIdx.x >> 6, lane = threadIdx.x & 63;
    const int ovn = *ovcnt;
    for (int i = blockIdx.x * NW + wave; i < ovn; i += gridDim.x * NW) {
        int e = ovlist[i];
        int r = row[e], c = col[e];
        float2 kvv = kv[(size_t)c * DIM + lane];
        float p = q[(size_t)r * DIM + lane] * kvv.x;
        p += __shfl_xor(p, 1, 64);
        p += __shfl_xor(p, 2, 64);
        float g = 0.5f * p * (1.0f + erff(p * 0.70710678118654752f));
        float a = g * radial[e];
        float m = kvv.y * edge_feat[(size_t)e * DIM + lane] * a;
        atomicAdd(&m_agg[(size_t)r * DIM + lane], m);
    }
}

// ---------------- Kernel C: aggregation + fused output projection ------------
// Branchless instruction-diet edge loop (round-5 counters: VALUBusy 56% was
// mostly pipeline machinery). Loads use clamped indices (always valid);
// padded-edge contributions are zeroed through rad=0. Attention scalar is
// broadcast within each head quad via width-4 shfl (lowers to DPP quad_perm).
// Only proven-green constructs: __shfl / nontemporal_load / erff.
__global__ __launch_bounds__(256) void agg_kernel(
    const float* __restrict__ q,
    const float2* __restrict__ kv,
    const float* __restrict__ edge_feat, // (E,64)
    const float* __restrict__ radial,
    const int2* __restrict__ perm2,
    const int* __restrict__ deg,
    const float* __restrict__ m_agg,     // overflow contributions only
    const float* __restrict__ input_dot,
    const float* __restrict__ out_w,     // (64,128) — L1-resident, not staged
    const float* __restrict__ out_b,     // (128,)
    float* __restrict__ result,          // (N,64)
    int N)
{
    __shared__ float accs[NW][64];       // 1 KB: per-wave row transpose
    const int wave = threadIdx.x >> 6, lane = threadIdx.x & 63;
    const int l3 = lane & 3;
    const float ob0 = out_b[lane], ob1 = out_b[lane + 64];
    const float2* kvl = kv + lane;            // loop-invariant lane offsets
    const float*  efl = edge_feat + lane;

#define ISSUE(J, S) do {                                                   \
        int jj_ = min((J), cnm1);                     /* always valid */   \
        int e_ = __shfl(myec.x, jj_, 64);                                  \
        int c_ = __shfl(myec.y, jj_, 64);                                  \
        kvq[S] = kvl[(size_t)(unsigned)c_ << 6];                           \
        eq[S]  = __builtin_nontemporal_load(efl + ((size_t)(unsigned)e_ << 6)); \
    } while (0)

    for (int n = blockIdx.x * NW + wave; n < N; n += gridDim.x * NW) {
        const int draw = deg[n];
        const int cn = min(draw, CAP);
        int2 myec = make_int2(0, 0);
        float myrad = 0.0f;
        if (lane < cn) {
            myec = perm2[(size_t)n * CAP + lane];   // coalesced 8B
            myrad = radial[myec.x];                 // 5 MB, cache-resident
        }
        const float qd = q[(n << 6) + lane];
        float idv = input_dot[(n << 6) + lane];     // early issue, used late

        float acc = 0.0f;
        if (cn > 0) {
            const int cnm1 = cn - 1;
            float2 kvq[PIPE]; float eq[PIPE];
            #pragma unroll
            for (int s = 0; s < PIPE; ++s) ISSUE(s, s);

            for (int j0 = 0; j0 < cn; j0 += PIPE) {
                float p[PIPE], ve[PIPE], rads[PIPE];
                #pragma unroll
                for (int s = 0; s < PIPE; ++s) {
                    const int j = j0 + s;
                    float kd = kvq[s].x, vd = kvq[s].y, ef = eq[s];
                    ISSUE(j + PIPE, s);             // refill stage early
                    ve[s] = vd * ef;
                    // uniform select: rad=0 zeroes padded-edge contributions
                    rads[s] = (j < cn) ? __shfl(myrad, min(j, cnm1), 64) : 0.0f;
                    float pp = qd * kd;
                    pp += __shfl_xor(pp, 1, 64);    // quad-local
                    pp += __shfl_xor(pp, 2, 64);    // head dot in all 4 lanes
                    p[s] = pp;
                }
                // one gelu serves 4 edges: lane l = edge (l&3), head (l>>2)
                float psel = l3 == 0 ? p[0] : l3 == 1 ? p[1]
                           : l3 == 2 ? p[2] : p[3];
                float rsel = l3 == 0 ? rads[0] : l3 == 1 ? rads[1]
                           : l3 == 2 ? rads[2] : rads[3];
                float aval = 0.5f * psel *
                             (1.0f + erff(psel * 0.70710678118654752f)) * rsel;
                // broadcast edge-s scalar across each head quad (DPP quad_perm)
                acc = fmaf(ve[0], __shfl(aval, 0, 4), acc);
                acc = fmaf(ve[1], __shfl(aval, 1, 4), acc);
                acc = fmaf(ve[2], __shfl(aval, 2, 4), acc);
                acc = fmaf(ve[3], __shfl(aval, 3, 4), acc);
            }
        }

        // wave-uniform, ~never-taken: fold in overflow atomics
        if (draw > CAP) acc += m_agg[(n << 6) + lane];

        // ---- fused output projection: out = acc_row @ out_w + out_b ----
        accs[wave][lane] = acc;                     // same-wave LDS transpose
        float o0 = ob0, o1 = ob1;
        #pragma unroll 8
        for (int d = 0; d < 64; ++d) {
            float md = accs[wave][d];               // LDS broadcast
            o0 = fmaf(md, out_w[d * 128 + lane], o0);
            o1 = fmaf(md, out_w[d * 128 + 64 + lane], o1);
        }
        result[(n << 6) + lane] = idv * o0 + o1;
    }
#undef ISSUE
}

extern "C" void kernel_launch(void* const* d_in, const int* in_sizes, int n_in,
                              void* d_out, int out_size, void* d_ws, size_t ws_size,
                              hipStream_t stream)
{
    const float* node_feat = (const float*)d_in[0];
    const float* edge_feat = (const float*)d_in[1];
    const float* node_vec  = (const float*)d_in[2];
    const float* radial    = (const float*)d_in[3];
    const float* ln_g      = (const float*)d_in[4];
    const float* ln_b      = (const float*)d_in[5];
    const float* qkv_w     = (const float*)d_in[6];
    const float* qkv_b     = (const float*)d_in[7];
    const float* vec_w     = (const float*)d_in[8];
    const float* out_w     = (const float*)d_in[9];
    const float* out_b     = (const float*)d_in[10];
    const int*   row       = (const int*)d_in[11];
    const int*   col       = (const int*)d_in[12];

    const int N = in_sizes[0] / DIM;   // 50000
    const int E = in_sizes[3];         // 1250000

    float*  ws    = (float*)d_ws;
    float*  q     = ws;                                   // N*64
    float2* kv    = (float2*)(q + (size_t)N * DIM);       // N*64 float2
    float*  idot  = (float*)(kv + (size_t)N * DIM);       // N*64
    float*  m_agg = idot + (size_t)N * DIM;               // N*64
    int2*   perm2 = (int2*)(m_agg + (size_t)N * DIM);     // N*CAP int2
    int*    deg   = (int*)(perm2 + (size_t)N * CAP);      // N ints
    int*    ovcnt = deg + N;                              // 1 int
    int*    ovlist= ovcnt + 1;                            // E ints

    const int grid_nodes = 768;
    const int grid_agg   = (N + NW - 1) / NW;             // 1 row per wave

    // zero counters + m_agg (overflow-atomic target); graph-capturable
    hipMemsetAsync(m_agg, 0, (size_t)N * DIM * sizeof(float), stream);
    hipMemsetAsync(deg,   0, (size_t)(N + 1) * sizeof(int), stream);

    qkv_kernel<<<grid_nodes, 256, 0, stream>>>(node_feat, ln_g, ln_b,
                                               qkv_w, qkv_b, q, kv, N);
    vec_kernel<<<grid_nodes, 256, 0, stream>>>(node_vec, vec_w, idot,
                                               row, col, deg, perm2,
                                               ovcnt, ovlist, N, E);
    ovf_kernel<<<256, 256, 0, stream>>>(q, kv, edge_feat, radial,
                                        row, col, ovcnt, ovlist, m_agg);
    agg_kernel<<<grid_agg, 256, 0, stream>>>(q, kv, edge_feat, radial,
                                             perm2, deg, m_agg, idot,
                                             out_w, out_b, (float*)d_out, N);
}